// Round 2
// baseline (2679.249 us; speedup 1.0000x reference)
//
#include <hip/hip_runtime.h>
#include <hip/hip_bf16.h>

#define DDIM    128
#define NNODES  50000
#define NEDGES  800000
#define NLAYERS 3
#define LN_EPS  1e-5f

// ---------------------------------------------------------------------------
// K0: x = LayerNorm(node_emb * sqrt(D) + pos_table[pos]) -> fp32 x (in d_out)
// one wave (64 lanes) per node; lane handles dims {lane, lane+64}
// ---------------------------------------------------------------------------
__global__ __launch_bounds__(256) void embed_ln_kernel(
    const float* __restrict__ node_emb,
    const int* __restrict__ pos,
    const float* __restrict__ pos_table,
    const float* __restrict__ g,
    const float* __restrict__ b,
    float* __restrict__ x)
{
    int wid  = (blockIdx.x * blockDim.x + threadIdx.x) >> 6;
    int lane = threadIdx.x & 63;
    if (wid >= NNODES) return;

    const float scale = 11.313708498984761f;  // sqrt(128)
    int p = pos[wid];
    size_t base  = (size_t)wid * DDIM;
    size_t pbase = (size_t)p * DDIM;

    float v0 = node_emb[base + lane]      * scale + pos_table[pbase + lane];
    float v1 = node_emb[base + lane + 64] * scale + pos_table[pbase + lane + 64];

    float s  = v0 + v1;
    float s2 = v0 * v0 + v1 * v1;
    #pragma unroll
    for (int m = 32; m > 0; m >>= 1) {
        s  += __shfl_xor(s,  m, 64);
        s2 += __shfl_xor(s2, m, 64);
    }
    float mean = s * (1.0f / DDIM);
    float var  = s2 * (1.0f / DDIM) - mean * mean;
    float rstd = rsqrtf(var + LN_EPS);

    x[base + lane]      = (v0 - mean) * rstd * g[lane]      + b[lane];
    x[base + lane + 64] = (v1 - mean) * rstd * g[lane + 64] + b[lane + 64];
}

// ---------------------------------------------------------------------------
// K1: agg[dst] += x[src]   (one wave per edge, float2 per lane, fp32 atomics)
// ---------------------------------------------------------------------------
__global__ __launch_bounds__(256) void scatter_add_kernel(
    const int* __restrict__ edge,
    const float* __restrict__ x,
    float* __restrict__ agg)
{
    long long gid = (long long)blockIdx.x * blockDim.x + threadIdx.x;
    int e    = (int)(gid >> 6);
    int lane = (int)(gid & 63);
    if (e >= NEDGES) return;

    int s = edge[e];
    int d = edge[NEDGES + e];

    const float2* xs = (const float2*)(x + (size_t)s * DDIM);
    float2 v = xs[lane];
    float* ad = agg + (size_t)d * DDIM + lane * 2;
    atomicAdd(ad,     v.x);
    atomicAdd(ad + 1, v.y);
}

// ---------------------------------------------------------------------------
// K2: per node n:  h = relu(agg@Wl + bl + x@Wr);  x = LN(h + x)   (x in-place)
// one 128-thread block per node; x/agg rows staged in LDS
// ---------------------------------------------------------------------------
__global__ __launch_bounds__(128) void sage_layer_kernel(
    float* __restrict__ x,
    const float* __restrict__ agg,
    const float* __restrict__ Wl,   // [D,D]: Wl[k*D + t]
    const float* __restrict__ bl,   // [D]
    const float* __restrict__ Wr,   // [D,D]
    const float* __restrict__ g,
    const float* __restrict__ b)
{
    __shared__ float sx[DDIM];
    __shared__ float sa[DDIM];
    __shared__ float red[4];

    int n = blockIdx.x;
    int t = threadIdx.x;
    size_t base = (size_t)n * DDIM;

    sx[t] = x[base + t];
    sa[t] = agg[base + t];
    __syncthreads();

    float acc = bl[t];
    #pragma unroll 8
    for (int k = 0; k < DDIM; ++k) {
        acc += sa[k] * Wl[k * DDIM + t] + sx[k] * Wr[k * DDIM + t];
    }
    float h = fmaxf(acc, 0.0f) + sx[t];

    // block LayerNorm over 128 values (2 waves)
    float s = h, s2 = h * h;
    #pragma unroll
    for (int m = 32; m > 0; m >>= 1) {
        s  += __shfl_xor(s,  m, 64);
        s2 += __shfl_xor(s2, m, 64);
    }
    int w = t >> 6;
    if ((t & 63) == 0) { red[w * 2] = s; red[w * 2 + 1] = s2; }
    __syncthreads();
    float S  = red[0] + red[2];
    float S2 = red[1] + red[3];
    float mean = S * (1.0f / DDIM);
    float var  = S2 * (1.0f / DDIM) - mean * mean;
    float rstd = rsqrtf(var + LN_EPS);

    x[base + t] = (h - mean) * rstd * g[t] + b[t];
}

// ---------------------------------------------------------------------------
extern "C" void kernel_launch(void* const* d_in, const int* in_sizes, int n_in,
                              void* d_out, int out_size, void* d_ws, size_t ws_size,
                              hipStream_t stream)
{
    const float* node_emb = (const float*)d_in[0];
    const int*   pos      = (const int*)d_in[1];
    const int*   edge     = (const int*)d_in[2];
    const float* pos_tab  = (const float*)d_in[3];
    const float* Wl       = (const float*)d_in[4];
    const float* bl       = (const float*)d_in[5];
    const float* Wr       = (const float*)d_in[6];
    const float* eg       = (const float*)d_in[7];
    const float* eb       = (const float*)d_in[8];
    const float* hg       = (const float*)d_in[9];
    const float* hb       = (const float*)d_in[10];

    // x lives directly in d_out (N*D fp32); final layer's x IS the output.
    float* x   = (float*)d_out;
    float* agg = (float*)d_ws;   // N*D fp32 = 25.6 MB scratch

    // K0: embedding + LN
    {
        int blocks = (NNODES * 64 + 255) / 256;   // 12500
        embed_ln_kernel<<<blocks, 256, 0, stream>>>(node_emb, pos, pos_tab, eg, eb, x);
    }

    for (int l = 0; l < NLAYERS; ++l) {
        hipMemsetAsync(agg, 0, (size_t)NNODES * DDIM * sizeof(float), stream);

        {
            long long threads = (long long)NEDGES * 64;
            int blocks = (int)((threads + 255) / 256);   // 200000
            scatter_add_kernel<<<blocks, 256, 0, stream>>>(edge, x, agg);
        }

        sage_layer_kernel<<<NNODES, 128, 0, stream>>>(
            x, agg,
            Wl + (size_t)l * DDIM * DDIM,
            bl + (size_t)l * DDIM,
            Wr + (size_t)l * DDIM * DDIM,
            hg + (size_t)l * DDIM,
            hb + (size_t)l * DDIM);
    }
}

// Round 3
// 689.636 us; speedup vs baseline: 3.8850x; 3.8850x over previous
//
#include <hip/hip_runtime.h>

#define DDIM    128
#define NNODES  50000
#define NEDGES  800000
#define NLAYERS 3
#define LN_EPS  1e-5f
#define NSCAN   ((NNODES + 255) / 256)   // 196 scan blocks

// ---------------------------------------------------------------------------
// CSR build: deg histogram -> block scan -> total scan -> add -> bucket fill
// ---------------------------------------------------------------------------
__global__ __launch_bounds__(256) void hist_kernel(
    const int* __restrict__ edge, int* __restrict__ deg)
{
    int e = blockIdx.x * 256 + threadIdx.x;
    if (e < NEDGES) atomicAdd(&deg[edge[NEDGES + e]], 1);
}

__global__ __launch_bounds__(256) void scan_part_kernel(
    const int* __restrict__ deg, int* __restrict__ offsets, int* __restrict__ partials)
{
    __shared__ int tmp[256];
    int t = threadIdx.x, i = blockIdx.x * 256 + t;
    int v = (i < NNODES) ? deg[i] : 0;
    tmp[t] = v; __syncthreads();
    for (int d = 1; d < 256; d <<= 1) {
        int add = (t >= d) ? tmp[t - d] : 0;
        __syncthreads();
        tmp[t] += add;
        __syncthreads();
    }
    if (i < NNODES) offsets[i + 1] = tmp[t];          // inclusive within block
    if (t == 255) partials[blockIdx.x] = tmp[255];
}

__global__ __launch_bounds__(256) void scan_tot_kernel(
    const int* __restrict__ partials, int* __restrict__ partoff)
{
    __shared__ int tmp[256];
    int t = threadIdx.x;
    int v = (t < NSCAN) ? partials[t] : 0;
    tmp[t] = v; __syncthreads();
    for (int d = 1; d < 256; d <<= 1) {
        int add = (t >= d) ? tmp[t - d] : 0;
        __syncthreads();
        tmp[t] += add;
        __syncthreads();
    }
    partoff[t] = tmp[t] - v;                          // exclusive scan
}

__global__ __launch_bounds__(256) void scan_add_kernel(
    int* __restrict__ offsets, const int* __restrict__ partoff)
{
    int t = threadIdx.x, i = blockIdx.x * 256 + t;
    if (i < NNODES) offsets[i + 1] += partoff[blockIdx.x];
    if (i == 0) offsets[0] = 0;
}

__global__ __launch_bounds__(256) void fill_kernel(
    const int* __restrict__ edge, const int* __restrict__ offsets,
    int* __restrict__ cursor, int* __restrict__ srcs)
{
    int e = blockIdx.x * 256 + threadIdx.x;
    if (e >= NEDGES) return;
    int d = edge[NEDGES + e];
    int s = edge[e];
    int slot = atomicAdd(&cursor[d], 1);
    srcs[offsets[d] + slot] = s;
}

// ---------------------------------------------------------------------------
// K0: x = LayerNorm(node_emb * sqrt(D) + pos_table[pos]) -> fp32 x (in d_out)
// one wave per node; lane handles dims {lane, lane+64}
// ---------------------------------------------------------------------------
__global__ __launch_bounds__(256) void embed_ln_kernel(
    const float* __restrict__ node_emb,
    const int* __restrict__ pos,
    const float* __restrict__ pos_table,
    const float* __restrict__ g,
    const float* __restrict__ b,
    float* __restrict__ x)
{
    int wid  = (blockIdx.x * blockDim.x + threadIdx.x) >> 6;
    int lane = threadIdx.x & 63;
    if (wid >= NNODES) return;

    const float scale = 11.313708498984761f;  // sqrt(128)
    int p = pos[wid];
    size_t base  = (size_t)wid * DDIM;
    size_t pbase = (size_t)p * DDIM;

    float v0 = node_emb[base + lane]      * scale + pos_table[pbase + lane];
    float v1 = node_emb[base + lane + 64] * scale + pos_table[pbase + lane + 64];

    float s  = v0 + v1;
    float s2 = v0 * v0 + v1 * v1;
    #pragma unroll
    for (int m = 32; m > 0; m >>= 1) {
        s  += __shfl_xor(s,  m, 64);
        s2 += __shfl_xor(s2, m, 64);
    }
    float mean = s * (1.0f / DDIM);
    float var  = s2 * (1.0f / DDIM) - mean * mean;
    float rstd = rsqrtf(var + LN_EPS);

    x[base + lane]      = (v0 - mean) * rstd * g[lane]      + b[lane];
    x[base + lane + 64] = (v1 - mean) * rstd * g[lane + 64] + b[lane + 64];
}

// ---------------------------------------------------------------------------
// K1: gather — agg[n] = sum over in-edges of x[src].  One wave per node,
// float2 per lane. No atomics, no agg memset.
// ---------------------------------------------------------------------------
__global__ __launch_bounds__(256) void gather_kernel(
    const int* __restrict__ offsets,
    const int* __restrict__ srcs,
    const float* __restrict__ x,
    float* __restrict__ agg)
{
    int wid  = (blockIdx.x * 256 + threadIdx.x) >> 6;   // node id
    int lane = threadIdx.x & 63;
    if (wid >= NNODES) return;

    int beg = offsets[wid];
    int end = offsets[wid + 1];
    float2 acc = make_float2(0.0f, 0.0f);
    for (int j = beg; j < end; ++j) {
        int s = __builtin_amdgcn_readfirstlane(srcs[j]);
        const float2 v = *(const float2*)(x + (size_t)s * DDIM + lane * 2);
        acc.x += v.x;
        acc.y += v.y;
    }
    *(float2*)(agg + (size_t)wid * DDIM + lane * 2) = acc;
}

// ---------------------------------------------------------------------------
// K2: 8 nodes per 128-thread block:
//     h = relu(agg@Wl + bl + x@Wr); x = LN(h + x)   (x in-place)
// ---------------------------------------------------------------------------
#define NPB 8
__global__ __launch_bounds__(128) void sage_layer_kernel(
    float* __restrict__ x,
    const float* __restrict__ agg,
    const float* __restrict__ Wl,   // [D,D]: Wl[k*D + t]
    const float* __restrict__ bl,   // [D]
    const float* __restrict__ Wr,   // [D,D]
    const float* __restrict__ g,
    const float* __restrict__ b)
{
    __shared__ __align__(16) float sx[NPB][DDIM];
    __shared__ __align__(16) float sa[NPB][DDIM];
    __shared__ __align__(16) float sh[NPB][DDIM];

    int t = threadIdx.x;
    size_t nb = (size_t)blockIdx.x * NPB;

    #pragma unroll
    for (int i = 0; i < NPB; ++i) {
        sx[i][t] = x[(nb + i) * DDIM + t];
        sa[i][t] = agg[(nb + i) * DDIM + t];
    }
    __syncthreads();

    float acc[NPB];
    float bias = bl[t];
    #pragma unroll
    for (int i = 0; i < NPB; ++i) acc[i] = bias;

    for (int k = 0; k < DDIM; k += 4) {
        float wl0 = Wl[(k + 0) * DDIM + t];
        float wl1 = Wl[(k + 1) * DDIM + t];
        float wl2 = Wl[(k + 2) * DDIM + t];
        float wl3 = Wl[(k + 3) * DDIM + t];
        float wr0 = Wr[(k + 0) * DDIM + t];
        float wr1 = Wr[(k + 1) * DDIM + t];
        float wr2 = Wr[(k + 2) * DDIM + t];
        float wr3 = Wr[(k + 3) * DDIM + t];
        #pragma unroll
        for (int i = 0; i < NPB; ++i) {
            float4 a  = *(const float4*)&sa[i][k];
            float4 xv = *(const float4*)&sx[i][k];
            acc[i] += a.x  * wl0 + a.y  * wl1 + a.z  * wl2 + a.w  * wl3
                    + xv.x * wr0 + xv.y * wr1 + xv.z * wr2 + xv.w * wr3;
        }
    }

    #pragma unroll
    for (int i = 0; i < NPB; ++i) sh[i][t] = fmaxf(acc[i], 0.0f) + sx[i][t];
    __syncthreads();

    // LN: wave w handles nodes [w*4, w*4+4), purely intra-wave reductions
    int w = t >> 6, lane = t & 63;
    for (int i = w * 4; i < w * 4 + 4; ++i) {
        float v0 = sh[i][lane], v1 = sh[i][lane + 64];
        float s = v0 + v1, s2 = v0 * v0 + v1 * v1;
        #pragma unroll
        for (int m = 32; m > 0; m >>= 1) {
            s  += __shfl_xor(s,  m, 64);
            s2 += __shfl_xor(s2, m, 64);
        }
        float mean = s * (1.0f / DDIM);
        float var  = s2 * (1.0f / DDIM) - mean * mean;
        float rstd = rsqrtf(var + LN_EPS);
        x[(nb + i) * DDIM + lane]      = (v0 - mean) * rstd * g[lane]      + b[lane];
        x[(nb + i) * DDIM + lane + 64] = (v1 - mean) * rstd * g[lane + 64] + b[lane + 64];
    }
}

// ---------------------------------------------------------------------------
extern "C" void kernel_launch(void* const* d_in, const int* in_sizes, int n_in,
                              void* d_out, int out_size, void* d_ws, size_t ws_size,
                              hipStream_t stream)
{
    const float* node_emb = (const float*)d_in[0];
    const int*   pos      = (const int*)d_in[1];
    const int*   edge     = (const int*)d_in[2];
    const float* pos_tab  = (const float*)d_in[3];
    const float* Wl       = (const float*)d_in[4];
    const float* bl       = (const float*)d_in[5];
    const float* Wr       = (const float*)d_in[6];
    const float* eg       = (const float*)d_in[7];
    const float* eb       = (const float*)d_in[8];
    const float* hg       = (const float*)d_in[9];
    const float* hb       = (const float*)d_in[10];

    // x lives in d_out (N*D fp32); final layer's x IS the output.
    float* x = (float*)d_out;

    // workspace layout (4B units):
    int* deg      = (int*)d_ws;            // NNODES
    int* cursor   = deg + NNODES;          // NNODES   (adjacent to deg: 1 memset)
    int* offsets  = cursor + NNODES;       // NNODES+2 (pad for alignment)
    int* partials = offsets + NNODES + 2;  // 256
    int* partoff  = partials + 256;        // 256
    int* srcs     = partoff + 256;         // NEDGES
    float* agg    = (float*)(srcs + NEDGES);  // NNODES*DDIM  (8B-aligned)

    // ---- CSR build (once per launch; edges constant across layers) ----
    hipMemsetAsync(deg, 0, 2 * NNODES * sizeof(int), stream);   // deg + cursor
    hist_kernel<<<(NEDGES + 255) / 256, 256, 0, stream>>>(edge, deg);
    scan_part_kernel<<<NSCAN, 256, 0, stream>>>(deg, offsets, partials);
    scan_tot_kernel<<<1, 256, 0, stream>>>(partials, partoff);
    scan_add_kernel<<<NSCAN, 256, 0, stream>>>(offsets, partoff);
    fill_kernel<<<(NEDGES + 255) / 256, 256, 0, stream>>>(edge, offsets, cursor, srcs);

    // ---- K0: embedding + LN ----
    embed_ln_kernel<<<(NNODES * 64 + 255) / 256, 256, 0, stream>>>(
        node_emb, pos, pos_tab, eg, eb, x);

    // ---- layers ----
    for (int l = 0; l < NLAYERS; ++l) {
        gather_kernel<<<(NNODES * 64 + 255) / 256, 256, 0, stream>>>(
            offsets, srcs, x, agg);

        sage_layer_kernel<<<NNODES / NPB, 128, 0, stream>>>(
            x, agg,
            Wl + (size_t)l * DDIM * DDIM,
            bl + (size_t)l * DDIM,
            Wr + (size_t)l * DDIM * DDIM,
            hg + (size_t)l * DDIM,
            hb + (size_t)l * DDIM);
    }
}

// Round 4
// 473.260 us; speedup vs baseline: 5.6613x; 1.4572x over previous
//
#include <hip/hip_runtime.h>
#include <hip/hip_bf16.h>

#define DDIM    128
#define NNODES  50000
#define NEDGES  800000
#define NLAYERS 3
#define LN_EPS  1e-5f
#define NSCAN   ((NNODES + 255) / 256)

typedef short s16x8 __attribute__((ext_vector_type(8)));
typedef float f32x4 __attribute__((ext_vector_type(4)));

__device__ __forceinline__ unsigned short f2bf(float f) {
    union { float f; unsigned u; } c; c.f = f;
    unsigned r = c.u + 0x7fff + ((c.u >> 16) & 1);   // RNE
    return (unsigned short)(r >> 16);
}
__device__ __forceinline__ float bf2f_u(unsigned short h) {
    union { unsigned u; float f; } c; c.u = (unsigned)h << 16;
    return c.f;
}

// ---------------------------------------------------------------------------
// CSR build
// ---------------------------------------------------------------------------
__global__ __launch_bounds__(256) void hist_kernel(
    const int* __restrict__ edge, int* __restrict__ deg)
{
    int e = blockIdx.x * 256 + threadIdx.x;
    if (e < NEDGES) atomicAdd(&deg[edge[NEDGES + e]], 1);
}

__global__ __launch_bounds__(256) void scan_part_kernel(
    const int* __restrict__ deg, int* __restrict__ offsets, int* __restrict__ partials)
{
    __shared__ int tmp[256];
    int t = threadIdx.x, i = blockIdx.x * 256 + t;
    int v = (i < NNODES) ? deg[i] : 0;
    tmp[t] = v; __syncthreads();
    for (int d = 1; d < 256; d <<= 1) {
        int add = (t >= d) ? tmp[t - d] : 0;
        __syncthreads();
        tmp[t] += add;
        __syncthreads();
    }
    if (i < NNODES) offsets[i + 1] = tmp[t];
    if (t == 255) partials[blockIdx.x] = tmp[255];
}

__global__ __launch_bounds__(256) void scan_tot_kernel(
    const int* __restrict__ partials, int* __restrict__ partoff)
{
    __shared__ int tmp[256];
    int t = threadIdx.x;
    int v = (t < NSCAN) ? partials[t] : 0;
    tmp[t] = v; __syncthreads();
    for (int d = 1; d < 256; d <<= 1) {
        int add = (t >= d) ? tmp[t - d] : 0;
        __syncthreads();
        tmp[t] += add;
        __syncthreads();
    }
    partoff[t] = tmp[t] - v;
}

__global__ __launch_bounds__(256) void scan_add_kernel(
    int* __restrict__ offsets, const int* __restrict__ partoff)
{
    int t = threadIdx.x, i = blockIdx.x * 256 + t;
    if (i < NNODES) offsets[i + 1] += partoff[blockIdx.x];
    if (i == 0) offsets[0] = 0;
}

__global__ __launch_bounds__(256) void fill_kernel(
    const int* __restrict__ edge, const int* __restrict__ offsets,
    int* __restrict__ cursor, int* __restrict__ srcs)
{
    int e = blockIdx.x * 256 + threadIdx.x;
    if (e >= NEDGES) return;
    int d = edge[NEDGES + e];
    int s = edge[e];
    int slot = atomicAdd(&cursor[d], 1);
    srcs[offsets[d] + slot] = s;
}

// ---------------------------------------------------------------------------
// K0: embed + LN -> x (fp32, d_out) AND xh (bf16 shadow)
// ---------------------------------------------------------------------------
__global__ __launch_bounds__(256) void embed_ln_kernel(
    const float* __restrict__ node_emb,
    const int* __restrict__ pos,
    const float* __restrict__ pos_table,
    const float* __restrict__ g,
    const float* __restrict__ b,
    float* __restrict__ x,
    unsigned short* __restrict__ xh)
{
    int wid  = (blockIdx.x * blockDim.x + threadIdx.x) >> 6;
    int lane = threadIdx.x & 63;
    if (wid >= NNODES) return;

    const float scale = 11.313708498984761f;
    int p = pos[wid];
    size_t base  = (size_t)wid * DDIM;
    size_t pbase = (size_t)p * DDIM;

    float v0 = node_emb[base + lane]      * scale + pos_table[pbase + lane];
    float v1 = node_emb[base + lane + 64] * scale + pos_table[pbase + lane + 64];

    float s  = v0 + v1;
    float s2 = v0 * v0 + v1 * v1;
    #pragma unroll
    for (int m = 32; m > 0; m >>= 1) {
        s  += __shfl_xor(s,  m, 64);
        s2 += __shfl_xor(s2, m, 64);
    }
    float mean = s * (1.0f / DDIM);
    float var  = s2 * (1.0f / DDIM) - mean * mean;
    float rstd = rsqrtf(var + LN_EPS);

    float y0 = (v0 - mean) * rstd * g[lane]      + b[lane];
    float y1 = (v1 - mean) * rstd * g[lane + 64] + b[lane + 64];
    x[base + lane]       = y0;
    x[base + lane + 64]  = y1;
    xh[base + lane]      = f2bf(y0);
    xh[base + lane + 64] = f2bf(y1);
}

// ---------------------------------------------------------------------------
// K1: gather (bf16): agg[n] = sum_{src} xh[src].  One wave per node,
// uint(=2×bf16) per lane; fp32 accumulate; bf16 store.
// ---------------------------------------------------------------------------
__global__ __launch_bounds__(256) void gather_kernel(
    const int* __restrict__ offsets,
    const int* __restrict__ srcs,
    const unsigned* __restrict__ xh32,     // xh as uint rows of 64
    unsigned* __restrict__ agg32)          // agg as uint rows of 64
{
    int wid  = (blockIdx.x * 256 + threadIdx.x) >> 6;
    int lane = threadIdx.x & 63;
    if (wid >= NNODES) return;

    int beg = offsets[wid];
    int end = offsets[wid + 1];
    float ax = 0.0f, ay = 0.0f;
    for (int j = beg; j < end; ++j) {
        int s = __builtin_amdgcn_readfirstlane(srcs[j]);
        unsigned u = xh32[(size_t)s * 64 + lane];
        ax += __uint_as_float(u << 16);
        ay += __uint_as_float(u & 0xffff0000u);
    }
    unsigned out = (unsigned)f2bf(ax) | ((unsigned)f2bf(ay) << 16);
    agg32[(size_t)wid * 64 + lane] = out;
}

// ---------------------------------------------------------------------------
// K2: MFMA sage layer.  Block = 256 thr (4 waves), 128 nodes/block.
// Fused GEMM: C[16n x 128c] = [agg|xh][16 x 256] @ [Wl;Wr][256 x 128]
// W staged in LDS in B-fragment order (fp32->bf16 in flight).
// Epilogue: +bias, relu, +x(fp32) residual, LayerNorm, store x fp32 + xh bf16.
// ---------------------------------------------------------------------------
__global__ __launch_bounds__(256) void sage_mfma_kernel(
    float* __restrict__ x,
    const unsigned short* __restrict__ agg,   // bf16 [N][128]
    const unsigned short* __restrict__ xh,    // bf16 [N][128]
    const float* __restrict__ Wl,             // fp32 [128][128]
    const float* __restrict__ bl,
    const float* __restrict__ Wr,             // fp32 [128][128]
    const float* __restrict__ g,
    const float* __restrict__ b,
    unsigned short* __restrict__ xh_out)      // bf16 shadow out
{
    __shared__ unsigned short wlds[8 * 8 * 64 * 8];   // 64 KB

    int t    = threadIdx.x;
    int wave = t >> 6;
    int lane = t & 63;
    int cl   = lane & 15;
    int q    = lane >> 4;

    // ---- stage W into LDS, B-frag order: entry(kt,ct,lane) = 8 bf16 of
    // Wcat[kt*32 + q*8 + j][ct*16 + cl], Wcat = [Wl; Wr] ----
    for (int idx = t; idx < 4096; idx += 256) {
        int kt = idx >> 9;
        int ct = (idx >> 6) & 7;
        int ln = idx & 63;
        int k0 = kt * 32 + ((ln >> 4) << 3);
        int c  = ct * 16 + (ln & 15);
        const float* Wsrc = (kt < 4) ? (Wl + k0 * DDIM + c)
                                     : (Wr + (k0 - 128) * DDIM + c);
        #pragma unroll
        for (int j = 0; j < 8; ++j)
            wlds[idx * 8 + j] = f2bf(Wsrc[j * DDIM]);
    }
    __syncthreads();

    // per-wave hoisted epilogue params (col = ct*16 + cl)
    float bias[8], gg[8], bb[8];
    #pragma unroll
    for (int ct = 0; ct < 8; ++ct) {
        int c = ct * 16 + cl;
        bias[ct] = bl[c]; gg[ct] = g[c]; bb[ct] = b[c];
    }

    int nb = blockIdx.x * 128;

    #pragma unroll
    for (int tile = 0; tile < 2; ++tile) {
        int m0 = nb + wave * 32 + tile * 16;
        int m  = m0 + cl;                       // A-operand row (m = lane&15)
        int mc = (m < NNODES) ? m : (NNODES - 1);

        // A fragments: kt 0..3 from agg, 4..7 from xh; 16B contiguous loads
        s16x8 af[8];
        #pragma unroll
        for (int kt = 0; kt < 4; ++kt)
            af[kt] = *(const s16x8*)(agg + (size_t)mc * DDIM + kt * 32 + q * 8);
        #pragma unroll
        for (int kt = 4; kt < 8; ++kt)
            af[kt] = *(const s16x8*)(xh + (size_t)mc * DDIM + (kt - 4) * 32 + q * 8);

        f32x4 acc[8];
        #pragma unroll
        for (int ct = 0; ct < 8; ++ct) acc[ct] = (f32x4){0.f, 0.f, 0.f, 0.f};

        #pragma unroll
        for (int kt = 0; kt < 8; ++kt) {
            #pragma unroll
            for (int ct = 0; ct < 8; ++ct) {
                s16x8 bf = *(const s16x8*)&wlds[(((kt << 3) + ct) << 6) * 8 + lane * 8];
                acc[ct] = __builtin_amdgcn_mfma_f32_16x16x32_bf16(af[kt], bf, acc[ct], 0, 0, 0);
            }
        }

        // ---- epilogue: C layout col = ct*16+cl, row(node) = m0 + q*4 + r ----
        float hbuf[8][4];
        #pragma unroll
        for (int ct = 0; ct < 8; ++ct) {
            #pragma unroll
            for (int r = 0; r < 4; ++r) {
                int node = m0 + q * 4 + r;
                int nc   = (node < NNODES) ? node : (NNODES - 1);
                float hv = fmaxf(acc[ct][r] + bias[ct], 0.0f);
                hbuf[ct][r] = hv + x[(size_t)nc * DDIM + ct * 16 + cl];
            }
        }

        float s[4], s2[4];
        #pragma unroll
        for (int r = 0; r < 4; ++r) {
            float a0 = 0.f, a1 = 0.f;
            #pragma unroll
            for (int ct = 0; ct < 8; ++ct) {
                a0 += hbuf[ct][r];
                a1 += hbuf[ct][r] * hbuf[ct][r];
            }
            #pragma unroll
            for (int msk = 1; msk < 16; msk <<= 1) {
                a0 += __shfl_xor(a0, msk, 64);
                a1 += __shfl_xor(a1, msk, 64);
            }
            s[r] = a0; s2[r] = a1;
        }

        #pragma unroll
        for (int r = 0; r < 4; ++r) {
            int node = m0 + q * 4 + r;
            if (node >= NNODES) continue;
            float mean = s[r] * (1.0f / DDIM);
            float var  = s2[r] * (1.0f / DDIM) - mean * mean;
            float rstd = rsqrtf(var + LN_EPS);
            #pragma unroll
            for (int ct = 0; ct < 8; ++ct) {
                float y = (hbuf[ct][r] - mean) * rstd * gg[ct] + bb[ct];
                size_t off = (size_t)node * DDIM + ct * 16 + cl;
                x[off]      = y;
                xh_out[off] = f2bf(y);
            }
        }
    }
}

// ---------------------------------------------------------------------------
extern "C" void kernel_launch(void* const* d_in, const int* in_sizes, int n_in,
                              void* d_out, int out_size, void* d_ws, size_t ws_size,
                              hipStream_t stream)
{
    const float* node_emb = (const float*)d_in[0];
    const int*   pos      = (const int*)d_in[1];
    const int*   edge     = (const int*)d_in[2];
    const float* pos_tab  = (const float*)d_in[3];
    const float* Wl       = (const float*)d_in[4];
    const float* bl       = (const float*)d_in[5];
    const float* Wr       = (const float*)d_in[6];
    const float* eg       = (const float*)d_in[7];
    const float* eb       = (const float*)d_in[8];
    const float* hg       = (const float*)d_in[9];
    const float* hb       = (const float*)d_in[10];

    float* x = (float*)d_out;   // fp32 state lives in d_out

    // workspace: [xh bf16 12.8MB][agg bf16 12.8MB][CSR ints ~3.8MB]
    unsigned short* xh  = (unsigned short*)d_ws;
    unsigned short* agg = xh + (size_t)NNODES * DDIM;
    int* deg      = (int*)(agg + (size_t)NNODES * DDIM);
    int* cursor   = deg + NNODES;
    int* offsets  = cursor + NNODES;
    int* partials = offsets + NNODES + 2;
    int* partoff  = partials + 256;
    int* srcs     = partoff + 256;

    // ---- CSR build (edges constant across layers) ----
    hipMemsetAsync(deg, 0, 2 * NNODES * sizeof(int), stream);
    hist_kernel<<<(NEDGES + 255) / 256, 256, 0, stream>>>(edge, deg);
    scan_part_kernel<<<NSCAN, 256, 0, stream>>>(deg, offsets, partials);
    scan_tot_kernel<<<1, 256, 0, stream>>>(partials, partoff);
    scan_add_kernel<<<NSCAN, 256, 0, stream>>>(offsets, partoff);
    fill_kernel<<<(NEDGES + 255) / 256, 256, 0, stream>>>(edge, offsets, cursor, srcs);

    // ---- embed + LN ----
    embed_ln_kernel<<<(NNODES * 64 + 255) / 256, 256, 0, stream>>>(
        node_emb, pos, pos_tab, eg, eb, x, xh);

    // ---- layers ----
    for (int l = 0; l < NLAYERS; ++l) {
        gather_kernel<<<(NNODES * 64 + 255) / 256, 256, 0, stream>>>(
            offsets, srcs, (const unsigned*)xh, (unsigned*)agg);

        sage_mfma_kernel<<<(NNODES + 127) / 128, 256, 0, stream>>>(
            x, agg, xh,
            Wl + (size_t)l * DDIM * DDIM,
            bl + (size_t)l * DDIM,
            Wr + (size_t)l * DDIM * DDIM,
            hg + (size_t)l * DDIM,
            hb + (size_t)l * DDIM,
            xh);
    }
}

// Round 5
// 357.372 us; speedup vs baseline: 7.4971x; 1.3243x over previous
//
#include <hip/hip_runtime.h>
#include <hip/hip_bf16.h>

#define DDIM    128
#define NNODES  50000
#define NEDGES  800000
#define NLAYERS 3
#define LN_EPS  1e-5f
#define NSCAN   ((NNODES + 255) / 256)

typedef short s16x8 __attribute__((ext_vector_type(8)));
typedef float f32x4 __attribute__((ext_vector_type(4)));

__device__ __forceinline__ unsigned short f2bf(float f) {
    union { float f; unsigned u; } c; c.f = f;
    unsigned r = c.u + 0x7fff + ((c.u >> 16) & 1);   // RNE
    return (unsigned short)(r >> 16);
}

// ---------------------------------------------------------------------------
// CSR build
// ---------------------------------------------------------------------------
__global__ __launch_bounds__(256) void hist_kernel(
    const int* __restrict__ edge, int* __restrict__ deg)
{
    int e = blockIdx.x * 256 + threadIdx.x;
    if (e < NEDGES) atomicAdd(&deg[edge[NEDGES + e]], 1);
}

__global__ __launch_bounds__(256) void scan_part_kernel(
    const int* __restrict__ deg, int* __restrict__ offsets, int* __restrict__ partials)
{
    __shared__ int tmp[256];
    int t = threadIdx.x, i = blockIdx.x * 256 + t;
    int v = (i < NNODES) ? deg[i] : 0;
    tmp[t] = v; __syncthreads();
    for (int d = 1; d < 256; d <<= 1) {
        int add = (t >= d) ? tmp[t - d] : 0;
        __syncthreads();
        tmp[t] += add;
        __syncthreads();
    }
    if (i < NNODES) offsets[i + 1] = tmp[t];
    if (t == 255) partials[blockIdx.x] = tmp[255];
}

__global__ __launch_bounds__(256) void scan_tot_kernel(
    const int* __restrict__ partials, int* __restrict__ partoff)
{
    __shared__ int tmp[256];
    int t = threadIdx.x;
    int v = (t < NSCAN) ? partials[t] : 0;
    tmp[t] = v; __syncthreads();
    for (int d = 1; d < 256; d <<= 1) {
        int add = (t >= d) ? tmp[t - d] : 0;
        __syncthreads();
        tmp[t] += add;
        __syncthreads();
    }
    partoff[t] = tmp[t] - v;
}

__global__ __launch_bounds__(256) void scan_add_kernel(
    int* __restrict__ offsets, const int* __restrict__ partoff)
{
    int t = threadIdx.x, i = blockIdx.x * 256 + t;
    if (i < NNODES) offsets[i + 1] += partoff[blockIdx.x];
    if (i == 0) offsets[0] = 0;
}

__global__ __launch_bounds__(256) void fill_kernel(
    const int* __restrict__ edge, const int* __restrict__ offsets,
    int* __restrict__ cursor, int* __restrict__ srcs)
{
    int e = blockIdx.x * 256 + threadIdx.x;
    if (e >= NEDGES) return;
    int d = edge[NEDGES + e];
    int s = edge[e];
    int slot = atomicAdd(&cursor[d], 1);
    srcs[offsets[d] + slot] = s;
}

// ---------------------------------------------------------------------------
// K0: embed + LN -> x (fp32, d_out) AND xh (bf16 shadow)
// ---------------------------------------------------------------------------
__global__ __launch_bounds__(256) void embed_ln_kernel(
    const float* __restrict__ node_emb,
    const int* __restrict__ pos,
    const float* __restrict__ pos_table,
    const float* __restrict__ g,
    const float* __restrict__ b,
    float* __restrict__ x,
    unsigned short* __restrict__ xh)
{
    int wid  = (blockIdx.x * blockDim.x + threadIdx.x) >> 6;
    int lane = threadIdx.x & 63;
    if (wid >= NNODES) return;

    const float scale = 11.313708498984761f;
    int p = pos[wid];
    size_t base  = (size_t)wid * DDIM;
    size_t pbase = (size_t)p * DDIM;

    float v0 = node_emb[base + lane]      * scale + pos_table[pbase + lane];
    float v1 = node_emb[base + lane + 64] * scale + pos_table[pbase + lane + 64];

    float s  = v0 + v1;
    float s2 = v0 * v0 + v1 * v1;
    #pragma unroll
    for (int m = 32; m > 0; m >>= 1) {
        s  += __shfl_xor(s,  m, 64);
        s2 += __shfl_xor(s2, m, 64);
    }
    float mean = s * (1.0f / DDIM);
    float var  = s2 * (1.0f / DDIM) - mean * mean;
    float rstd = rsqrtf(var + LN_EPS);

    float y0 = (v0 - mean) * rstd * g[lane]      + b[lane];
    float y1 = (v1 - mean) * rstd * g[lane + 64] + b[lane + 64];
    x[base + lane]       = y0;
    x[base + lane + 64]  = y1;
    xh[base + lane]      = f2bf(y0);
    xh[base + lane + 64] = f2bf(y1);
}

// ---------------------------------------------------------------------------
// K1: gather (bf16): agg[n] = sum_{src} xh[src].  One wave per node.
// 4x unrolled neighbor loop: 4 independent row loads in flight per wave.
// ---------------------------------------------------------------------------
__global__ __launch_bounds__(256) void gather_kernel(
    const int* __restrict__ offsets,
    const int* __restrict__ srcs,
    const unsigned* __restrict__ xh32,     // xh as uint rows of 64
    unsigned* __restrict__ agg32)          // agg as uint rows of 64
{
    int wid  = (blockIdx.x * 256 + threadIdx.x) >> 6;
    int lane = threadIdx.x & 63;
    if (wid >= NNODES) return;

    int beg = offsets[wid];
    int end = offsets[wid + 1];
    float ax = 0.0f, ay = 0.0f;

    int j = beg;
    for (; j + 4 <= end; j += 4) {
        int s0 = srcs[j], s1 = srcs[j + 1], s2 = srcs[j + 2], s3 = srcs[j + 3];
        unsigned u0 = xh32[(size_t)s0 * 64 + lane];
        unsigned u1 = xh32[(size_t)s1 * 64 + lane];
        unsigned u2 = xh32[(size_t)s2 * 64 + lane];
        unsigned u3 = xh32[(size_t)s3 * 64 + lane];
        ax += __uint_as_float(u0 << 16);
        ay += __uint_as_float(u0 & 0xffff0000u);
        ax += __uint_as_float(u1 << 16);
        ay += __uint_as_float(u1 & 0xffff0000u);
        ax += __uint_as_float(u2 << 16);
        ay += __uint_as_float(u2 & 0xffff0000u);
        ax += __uint_as_float(u3 << 16);
        ay += __uint_as_float(u3 & 0xffff0000u);
    }
    for (; j < end; ++j) {
        unsigned u = xh32[(size_t)srcs[j] * 64 + lane];
        ax += __uint_as_float(u << 16);
        ay += __uint_as_float(u & 0xffff0000u);
    }

    unsigned out = (unsigned)f2bf(ax) | ((unsigned)f2bf(ay) << 16);
    agg32[(size_t)wid * 64 + lane] = out;
}

// ---------------------------------------------------------------------------
// K2: MFMA sage layer.  Block = 256 thr (4 waves), 128 nodes/block.
// Fused GEMM: C[16n x 128c] = [agg|xh][16 x 256] @ [Wl;Wr][256 x 128]
// W staged in LDS in B-fragment order (fp32->bf16 in flight).
// Epilogue: +bias, relu, +x(fp32) residual, LayerNorm, store x fp32 + xh bf16.
// ---------------------------------------------------------------------------
__global__ __launch_bounds__(256) void sage_mfma_kernel(
    float* __restrict__ x,
    const unsigned short* __restrict__ agg,   // bf16 [N][128]
    const unsigned short* __restrict__ xh,    // bf16 [N][128]
    const float* __restrict__ Wl,             // fp32 [128][128]
    const float* __restrict__ bl,
    const float* __restrict__ Wr,             // fp32 [128][128]
    const float* __restrict__ g,
    const float* __restrict__ b,
    unsigned short* __restrict__ xh_out)      // bf16 shadow out
{
    __shared__ unsigned short wlds[8 * 8 * 64 * 8];   // 64 KB

    int t    = threadIdx.x;
    int wave = t >> 6;
    int lane = t & 63;
    int cl   = lane & 15;
    int q    = lane >> 4;

    // ---- stage W into LDS, B-frag order: entry(kt,ct,lane) = 8 bf16 of
    // Wcat[kt*32 + q*8 + j][ct*16 + cl], Wcat = [Wl; Wr] ----
    for (int idx = t; idx < 4096; idx += 256) {
        int kt = idx >> 9;
        int ct = (idx >> 6) & 7;
        int ln = idx & 63;
        int k0 = kt * 32 + ((ln >> 4) << 3);
        int c  = ct * 16 + (ln & 15);
        const float* Wsrc = (kt < 4) ? (Wl + k0 * DDIM + c)
                                     : (Wr + (k0 - 128) * DDIM + c);
        #pragma unroll
        for (int j = 0; j < 8; ++j)
            wlds[idx * 8 + j] = f2bf(Wsrc[j * DDIM]);
    }
    __syncthreads();

    // per-wave hoisted epilogue params (col = ct*16 + cl)
    float bias[8], gg[8], bb[8];
    #pragma unroll
    for (int ct = 0; ct < 8; ++ct) {
        int c = ct * 16 + cl;
        bias[ct] = bl[c]; gg[ct] = g[c]; bb[ct] = b[c];
    }

    int nb = blockIdx.x * 128;

    #pragma unroll
    for (int tile = 0; tile < 2; ++tile) {
        int m0 = nb + wave * 32 + tile * 16;
        int m  = m0 + cl;                       // A-operand row (m = lane&15)
        int mc = (m < NNODES) ? m : (NNODES - 1);

        // A fragments: kt 0..3 from agg, 4..7 from xh; 16B contiguous loads
        s16x8 af[8];
        #pragma unroll
        for (int kt = 0; kt < 4; ++kt)
            af[kt] = *(const s16x8*)(agg + (size_t)mc * DDIM + kt * 32 + q * 8);
        #pragma unroll
        for (int kt = 4; kt < 8; ++kt)
            af[kt] = *(const s16x8*)(xh + (size_t)mc * DDIM + (kt - 4) * 32 + q * 8);

        f32x4 acc[8];
        #pragma unroll
        for (int ct = 0; ct < 8; ++ct) acc[ct] = (f32x4){0.f, 0.f, 0.f, 0.f};

        #pragma unroll
        for (int kt = 0; kt < 8; ++kt) {
            #pragma unroll
            for (int ct = 0; ct < 8; ++ct) {
                s16x8 bf = *(const s16x8*)&wlds[(((kt << 3) + ct) << 6) * 8 + lane * 8];
                acc[ct] = __builtin_amdgcn_mfma_f32_16x16x32_bf16(af[kt], bf, acc[ct], 0, 0, 0);
            }
        }

        // ---- epilogue: C layout col = ct*16+cl, row(node) = m0 + q*4 + r ----
        float hbuf[8][4];
        #pragma unroll
        for (int ct = 0; ct < 8; ++ct) {
            #pragma unroll
            for (int r = 0; r < 4; ++r) {
                int node = m0 + q * 4 + r;
                int nc   = (node < NNODES) ? node : (NNODES - 1);
                float hv = fmaxf(acc[ct][r] + bias[ct], 0.0f);
                hbuf[ct][r] = hv + x[(size_t)nc * DDIM + ct * 16 + cl];
            }
        }

        float s[4], s2[4];
        #pragma unroll
        for (int r = 0; r < 4; ++r) {
            float a0 = 0.f, a1 = 0.f;
            #pragma unroll
            for (int ct = 0; ct < 8; ++ct) {
                a0 += hbuf[ct][r];
                a1 += hbuf[ct][r] * hbuf[ct][r];
            }
            #pragma unroll
            for (int msk = 1; msk < 16; msk <<= 1) {
                a0 += __shfl_xor(a0, msk, 64);
                a1 += __shfl_xor(a1, msk, 64);
            }
            s[r] = a0; s2[r] = a1;
        }

        #pragma unroll
        for (int r = 0; r < 4; ++r) {
            int node = m0 + q * 4 + r;
            if (node >= NNODES) continue;
            float mean = s[r] * (1.0f / DDIM);
            float var  = s2[r] * (1.0f / DDIM) - mean * mean;
            float rstd = rsqrtf(var + LN_EPS);
            #pragma unroll
            for (int ct = 0; ct < 8; ++ct) {
                float y = (hbuf[ct][r] - mean) * rstd * gg[ct] + bb[ct];
                size_t off = (size_t)node * DDIM + ct * 16 + cl;
                x[off]      = y;
                xh_out[off] = f2bf(y);
            }
        }
    }
}

// ---------------------------------------------------------------------------
extern "C" void kernel_launch(void* const* d_in, const int* in_sizes, int n_in,
                              void* d_out, int out_size, void* d_ws, size_t ws_size,
                              hipStream_t stream)
{
    const float* node_emb = (const float*)d_in[0];
    const int*   pos      = (const int*)d_in[1];
    const int*   edge     = (const int*)d_in[2];
    const float* pos_tab  = (const float*)d_in[3];
    const float* Wl       = (const float*)d_in[4];
    const float* bl       = (const float*)d_in[5];
    const float* Wr       = (const float*)d_in[6];
    const float* eg       = (const float*)d_in[7];
    const float* eb       = (const float*)d_in[8];
    const float* hg       = (const float*)d_in[9];
    const float* hb       = (const float*)d_in[10];

    float* x = (float*)d_out;   // fp32 state lives in d_out

    // workspace: [xh bf16 12.8MB][agg bf16 12.8MB][CSR ints ~3.8MB]
    unsigned short* xh  = (unsigned short*)d_ws;
    unsigned short* agg = xh + (size_t)NNODES * DDIM;
    int* deg      = (int*)(agg + (size_t)NNODES * DDIM);
    int* cursor   = deg + NNODES;
    int* offsets  = cursor + NNODES;
    int* partials = offsets + NNODES + 2;
    int* partoff  = partials + 256;
    int* srcs     = partoff + 256;

    // ---- CSR build (edges constant across layers) ----
    hipMemsetAsync(deg, 0, 2 * NNODES * sizeof(int), stream);
    hist_kernel<<<(NEDGES + 255) / 256, 256, 0, stream>>>(edge, deg);
    scan_part_kernel<<<NSCAN, 256, 0, stream>>>(deg, offsets, partials);
    scan_tot_kernel<<<1, 256, 0, stream>>>(partials, partoff);
    scan_add_kernel<<<NSCAN, 256, 0, stream>>>(offsets, partoff);
    fill_kernel<<<(NEDGES + 255) / 256, 256, 0, stream>>>(edge, offsets, cursor, srcs);

    // ---- embed + LN ----
    embed_ln_kernel<<<(NNODES * 64 + 255) / 256, 256, 0, stream>>>(
        node_emb, pos, pos_tab, eg, eb, x, xh);

    // ---- layers ----
    for (int l = 0; l < NLAYERS; ++l) {
        gather_kernel<<<(NNODES * 64 + 255) / 256, 256, 0, stream>>>(
            offsets, srcs, (const unsigned*)xh, (unsigned*)agg);

        sage_mfma_kernel<<<(NNODES + 127) / 128, 256, 0, stream>>>(
            x, agg, xh,
            Wl + (size_t)l * DDIM * DDIM,
            bl + (size_t)l * DDIM,
            Wr + (size_t)l * DDIM * DDIM,
            hg + (size_t)l * DDIM,
            hb + (size_t)l * DDIM,
            xh);
    }
}

// Round 6
// 349.737 us; speedup vs baseline: 7.6608x; 1.0218x over previous
//
#include <hip/hip_runtime.h>

#define DDIM    128
#define NNODES  50000
#define NEDGES  800000
#define NLAYERS 3
#define LN_EPS  1e-5f
#define NSCAN   ((NNODES + 255) / 256)
#define NSLICE  8
#define SLICESZ ((NNODES + NSLICE - 1) / NSLICE)              // 6250
#define FILL_EPT 8
#define FILL_CHUNK (256 * FILL_EPT)                           // 2048
#define FILL_NCHUNK ((NEDGES + FILL_CHUNK - 1) / FILL_CHUNK)  // 391

typedef short s16x8 __attribute__((ext_vector_type(8)));
typedef float f32x4 __attribute__((ext_vector_type(4)));
typedef unsigned int u32;

__device__ __forceinline__ unsigned short f2bf(float f) {
    union { float f; unsigned u; } c; c.f = f;
    unsigned r = c.u + 0x7fff + ((c.u >> 16) & 1);   // RNE
    return (unsigned short)(r >> 16);
}
__device__ __forceinline__ float bf2f_u(unsigned short h) {
    union { unsigned u; float f; } c; c.u = (unsigned)h << 16;
    return c.f;
}
__device__ __forceinline__ float bflo(u32 v) { return __uint_as_float(v << 16); }
__device__ __forceinline__ float bfhi(u32 v) { return __uint_as_float(v & 0xffff0000u); }

// ---------------------------------------------------------------------------
// CSR build
// ---------------------------------------------------------------------------
__global__ __launch_bounds__(256) void hist_kernel(
    const int* __restrict__ edge, int* __restrict__ deg)
{
    int e = blockIdx.x * 256 + threadIdx.x;
    if (e < NEDGES) atomicAdd(&deg[edge[NEDGES + e]], 1);
}

__global__ __launch_bounds__(256) void scan_part_kernel(
    const int* __restrict__ deg, int* __restrict__ offsets, int* __restrict__ partials)
{
    __shared__ int tmp[256];
    int t = threadIdx.x, i = blockIdx.x * 256 + t;
    int v = (i < NNODES) ? deg[i] : 0;
    tmp[t] = v; __syncthreads();
    for (int d = 1; d < 256; d <<= 1) {
        int add = (t >= d) ? tmp[t - d] : 0;
        __syncthreads();
        tmp[t] += add;
        __syncthreads();
    }
    if (i < NNODES) offsets[i + 1] = tmp[t];
    if (t == 255) partials[blockIdx.x] = tmp[255];
}

__global__ __launch_bounds__(256) void scan_tot_kernel(
    const int* __restrict__ partials, int* __restrict__ partoff)
{
    __shared__ int tmp[256];
    int t = threadIdx.x;
    int v = (t < NSCAN) ? partials[t] : 0;
    tmp[t] = v; __syncthreads();
    for (int d = 1; d < 256; d <<= 1) {
        int add = (t >= d) ? tmp[t - d] : 0;
        __syncthreads();
        tmp[t] += add;
        __syncthreads();
    }
    partoff[t] = tmp[t] - v;
}

__global__ __launch_bounds__(256) void scan_add_kernel(
    int* __restrict__ offsets, const int* __restrict__ partoff)
{
    int t = threadIdx.x, i = blockIdx.x * 256 + t;
    if (i < NNODES) offsets[i + 1] += partoff[blockIdx.x];
    if (i == 0) offsets[0] = 0;
}

// XCD-sliced fill: block b -> dst slice (b&7), edge chunk (b>>3).
// srcs lines (dst-contiguous in CSR) get written by one XCD only.
__global__ __launch_bounds__(256) void fill_kernel(
    const int* __restrict__ edge, const int* __restrict__ offsets,
    int* __restrict__ cursor, int* __restrict__ srcs)
{
    int slice = blockIdx.x & (NSLICE - 1);
    int chunk = blockIdx.x >> 3;
    int lo = slice * SLICESZ;
    int hi = lo + SLICESZ;
    int base = chunk * FILL_CHUNK + threadIdx.x;
    #pragma unroll
    for (int i = 0; i < FILL_EPT; ++i) {
        int e = base + i * 256;
        if (e < NEDGES) {
            int d = edge[NEDGES + e];
            if (d >= lo && d < hi) {
                int s = edge[e];
                int slot = atomicAdd(&cursor[d], 1);
                srcs[offsets[d] + slot] = s;
            }
        }
    }
}

// ---------------------------------------------------------------------------
// Wcat prepack: [Wl;Wr] fp32 -> bf16 in MFMA B-fragment order, per layer.
// entry(kt,ct,ln) element j = Wcat[kt*32 + (ln>>4)*8 + j][ct*16 + (ln&15)]
// ---------------------------------------------------------------------------
__global__ __launch_bounds__(256) void wpack_kernel(
    const float* __restrict__ Wl,            // [L][128][128]
    const float* __restrict__ Wr,            // [L][128][128]
    unsigned short* __restrict__ wpk)        // [L][4096*8]
{
    int idx = blockIdx.x * 256 + threadIdx.x;
    if (idx >= NLAYERS * 4096) return;
    int l   = idx >> 12;
    int rem = idx & 4095;
    int kt = rem >> 9, ct = (rem >> 6) & 7, ln = rem & 63;
    int k0 = kt * 32 + ((ln >> 4) << 3);
    int c  = ct * 16 + (ln & 15);
    const float* src = (kt < 4)
        ? Wl + (size_t)l * DDIM * DDIM + (size_t)k0 * DDIM + c
        : Wr + (size_t)l * DDIM * DDIM + (size_t)(k0 - 128) * DDIM + c;
    s16x8 o;
    #pragma unroll
    for (int j = 0; j < 8; ++j) o[j] = (short)f2bf(src[j * DDIM]);
    *(s16x8*)(wpk + (size_t)idx * 8) = o;
}

// ---------------------------------------------------------------------------
// K0: embed + LN -> xh (bf16 only; fp32 state eliminated)
// one wave per node; lane handles cols {2*lane, 2*lane+1} via float2
// ---------------------------------------------------------------------------
__global__ __launch_bounds__(256) void embed_ln_kernel(
    const float* __restrict__ node_emb,
    const int* __restrict__ pos,
    const float* __restrict__ pos_table,
    const float* __restrict__ g,
    const float* __restrict__ b,
    u32* __restrict__ xh32)
{
    int wid  = (blockIdx.x * blockDim.x + threadIdx.x) >> 6;
    int lane = threadIdx.x & 63;
    if (wid >= NNODES) return;

    const float scale = 11.313708498984761f;  // sqrt(128)
    int p = pos[wid];

    float2 ne = *(const float2*)(node_emb + (size_t)wid * DDIM + lane * 2);
    float2 pt = *(const float2*)(pos_table + (size_t)p * DDIM + lane * 2);
    float v0 = ne.x * scale + pt.x;
    float v1 = ne.y * scale + pt.y;

    float s  = v0 + v1;
    float s2 = v0 * v0 + v1 * v1;
    #pragma unroll
    for (int m = 32; m > 0; m >>= 1) {
        s  += __shfl_xor(s,  m, 64);
        s2 += __shfl_xor(s2, m, 64);
    }
    float mean = s * (1.0f / DDIM);
    float var  = s2 * (1.0f / DDIM) - mean * mean;
    float rstd = rsqrtf(var + LN_EPS);

    float2 gv = *(const float2*)(g + lane * 2);
    float2 bv = *(const float2*)(b + lane * 2);
    float y0 = (v0 - mean) * rstd * gv.x + bv.x;
    float y1 = (v1 - mean) * rstd * gv.y + bv.y;
    xh32[(size_t)wid * 64 + lane] = (u32)f2bf(y0) | ((u32)f2bf(y1) << 16);
}

// ---------------------------------------------------------------------------
// K1: gather, 16B/lane: wave per node; 16 lanes x 4 neighbors concurrently.
// lane (q,cl) loads uint4 (8 bf16 cols cl*8..cl*8+7) of neighbor j+q;
// 2 groups in flight; final cross-q shfl reduce; q==0 lanes store row.
// ---------------------------------------------------------------------------
__global__ __launch_bounds__(256) void gather_kernel(
    const int* __restrict__ offsets,
    const int* __restrict__ srcs,
    const uint4* __restrict__ xh4,     // row = 16 uint4
    uint4* __restrict__ agg4)
{
    int wid  = (blockIdx.x * 256 + threadIdx.x) >> 6;
    int lane = threadIdx.x & 63;
    if (wid >= NNODES) return;
    int q = lane >> 4, cl = lane & 15;

    int beg = offsets[wid];
    int end = offsets[wid + 1];

    float acc[8];
    #pragma unroll
    for (int k = 0; k < 8; ++k) acc[k] = 0.0f;

    for (int j = beg; j < end; j += 8) {
        int j0 = j + q, j1 = j + 4 + q;
        if (j0 < end) {
            uint4 u = xh4[(size_t)srcs[j0] * 16 + cl];
            acc[0] += bflo(u.x); acc[1] += bfhi(u.x);
            acc[2] += bflo(u.y); acc[3] += bfhi(u.y);
            acc[4] += bflo(u.z); acc[5] += bfhi(u.z);
            acc[6] += bflo(u.w); acc[7] += bfhi(u.w);
        }
        if (j1 < end) {
            uint4 u = xh4[(size_t)srcs[j1] * 16 + cl];
            acc[0] += bflo(u.x); acc[1] += bfhi(u.x);
            acc[2] += bflo(u.y); acc[3] += bfhi(u.y);
            acc[4] += bflo(u.z); acc[5] += bfhi(u.z);
            acc[6] += bflo(u.w); acc[7] += bfhi(u.w);
        }
    }

    #pragma unroll
    for (int k = 0; k < 8; ++k) {
        acc[k] += __shfl_xor(acc[k], 16, 64);
        acc[k] += __shfl_xor(acc[k], 32, 64);
    }

    if (q == 0) {
        uint4 o;
        o.x = (u32)f2bf(acc[0]) | ((u32)f2bf(acc[1]) << 16);
        o.y = (u32)f2bf(acc[2]) | ((u32)f2bf(acc[3]) << 16);
        o.z = (u32)f2bf(acc[4]) | ((u32)f2bf(acc[5]) << 16);
        o.w = (u32)f2bf(acc[6]) | ((u32)f2bf(acc[7]) << 16);
        agg4[(size_t)wid * 16 + cl] = o;
    }
}

// ---------------------------------------------------------------------------
// K2: MFMA sage layer, pure-bf16 state, 64 nodes/block (4 waves, 1 tile each).
// C[16 x 128] = [agg|xh][16 x 256] @ Wcat[256 x 128]; W prestaged (prepacked).
// Epilogue: +bias, relu, +bf16 residual, LN -> xh (in-place); fp32 out on last.
// ---------------------------------------------------------------------------
__global__ __launch_bounds__(256) void sage_mfma_kernel(
    const unsigned short* __restrict__ agg,   // bf16 [N][128]
    unsigned short* __restrict__ xh,          // bf16 [N][128], in/out
    const unsigned short* __restrict__ wpk,   // this layer, B-frag order
    const float* __restrict__ bl,
    const float* __restrict__ g,
    const float* __restrict__ b,
    float* __restrict__ xout)                 // d_out on last layer, else null
{
    __shared__ unsigned short wlds[4096 * 8];   // 64 KB

    int t    = threadIdx.x;
    int wave = t >> 6;
    int lane = t & 63;
    int cl   = lane & 15;
    int q    = lane >> 4;

    // stage prepacked W: linear 64 KB vector copy
    {
        const s16x8* srcv = (const s16x8*)wpk;
        s16x8* dstv = (s16x8*)wlds;
        for (int i = t; i < 4096; i += 256) dstv[i] = srcv[i];
    }
    __syncthreads();

    float bias[8], gg[8], bb[8];
    #pragma unroll
    for (int ct = 0; ct < 8; ++ct) {
        int c = ct * 16 + cl;
        bias[ct] = bl[c]; gg[ct] = g[c]; bb[ct] = b[c];
    }

    int m0 = blockIdx.x * 64 + wave * 16;
    int m  = m0 + cl;
    int mc = (m < NNODES) ? m : (NNODES - 1);

    s16x8 af[8];
    #pragma unroll
    for (int kt = 0; kt < 4; ++kt)
        af[kt] = *(const s16x8*)(agg + (size_t)mc * DDIM + kt * 32 + q * 8);
    #pragma unroll
    for (int kt = 4; kt < 8; ++kt)
        af[kt] = *(const s16x8*)(xh + (size_t)mc * DDIM + (kt - 4) * 32 + q * 8);

    f32x4 acc[8];
    #pragma unroll
    for (int ct = 0; ct < 8; ++ct) acc[ct] = (f32x4){0.f, 0.f, 0.f, 0.f};

    #pragma unroll
    for (int kt = 0; kt < 8; ++kt) {
        #pragma unroll
        for (int ct = 0; ct < 8; ++ct) {
            s16x8 bfr = *(const s16x8*)&wlds[((((kt << 3) + ct) << 6) + lane) * 8];
            acc[ct] = __builtin_amdgcn_mfma_f32_16x16x32_bf16(af[kt], bfr, acc[ct], 0, 0, 0);
        }
    }

    // epilogue: C layout col = ct*16+cl, row(node) = m0 + q*4 + r
    float hbuf[8][4];
    #pragma unroll
    for (int ct = 0; ct < 8; ++ct) {
        #pragma unroll
        for (int r = 0; r < 4; ++r) {
            int node = m0 + q * 4 + r;
            int nc   = (node < NNODES) ? node : (NNODES - 1);
            float hv = fmaxf(acc[ct][r] + bias[ct], 0.0f);
            hbuf[ct][r] = hv + bf2f_u(xh[(size_t)nc * DDIM + ct * 16 + cl]);
        }
    }

    float s[4], s2[4];
    #pragma unroll
    for (int r = 0; r < 4; ++r) {
        float a0 = 0.f, a1 = 0.f;
        #pragma unroll
        for (int ct = 0; ct < 8; ++ct) {
            a0 += hbuf[ct][r];
            a1 += hbuf[ct][r] * hbuf[ct][r];
        }
        #pragma unroll
        for (int msk = 1; msk < 16; msk <<= 1) {
            a0 += __shfl_xor(a0, msk, 64);
            a1 += __shfl_xor(a1, msk, 64);
        }
        s[r] = a0; s2[r] = a1;
    }

    #pragma unroll
    for (int r = 0; r < 4; ++r) {
        int node = m0 + q * 4 + r;
        if (node >= NNODES) continue;
        float mean = s[r] * (1.0f / DDIM);
        float var  = s2[r] * (1.0f / DDIM) - mean * mean;
        float rstd = rsqrtf(var + LN_EPS);
        #pragma unroll
        for (int ct = 0; ct < 8; ++ct) {
            float y = (hbuf[ct][r] - mean) * rstd * gg[ct] + bb[ct];
            size_t off = (size_t)node * DDIM + ct * 16 + cl;
            xh[off] = f2bf(y);
            if (xout) xout[off] = y;
        }
    }
}

// ---------------------------------------------------------------------------
extern "C" void kernel_launch(void* const* d_in, const int* in_sizes, int n_in,
                              void* d_out, int out_size, void* d_ws, size_t ws_size,
                              hipStream_t stream)
{
    const float* node_emb = (const float*)d_in[0];
    const int*   pos      = (const int*)d_in[1];
    const int*   edge     = (const int*)d_in[2];
    const float* pos_tab  = (const float*)d_in[3];
    const float* Wl       = (const float*)d_in[4];
    const float* bl       = (const float*)d_in[5];
    const float* Wr       = (const float*)d_in[6];
    const float* eg       = (const float*)d_in[7];
    const float* eb       = (const float*)d_in[8];
    const float* hg       = (const float*)d_in[9];
    const float* hb       = (const float*)d_in[10];

    // workspace: [xh bf16][agg bf16][wpk bf16][CSR ints]
    unsigned short* xh  = (unsigned short*)d_ws;
    unsigned short* agg = xh + (size_t)NNODES * DDIM;
    unsigned short* wpk = agg + (size_t)NNODES * DDIM;
    int* deg      = (int*)(wpk + (size_t)NLAYERS * 4096 * 8);
    int* cursor   = deg + NNODES;
    int* offsets  = cursor + NNODES;
    int* partials = offsets + NNODES + 2;
    int* partoff  = partials + 256;
    int* srcs     = partoff + 256;

    // ---- CSR build (edges constant across layers) ----
    hipMemsetAsync(deg, 0, 2 * NNODES * sizeof(int), stream);
    hist_kernel<<<(NEDGES + 255) / 256, 256, 0, stream>>>(edge, deg);
    scan_part_kernel<<<NSCAN, 256, 0, stream>>>(deg, offsets, partials);
    scan_tot_kernel<<<1, 256, 0, stream>>>(partials, partoff);
    scan_add_kernel<<<NSCAN, 256, 0, stream>>>(offsets, partoff);
    fill_kernel<<<FILL_NCHUNK * NSLICE, 256, 0, stream>>>(edge, offsets, cursor, srcs);

    // ---- W prepack (all layers) ----
    wpack_kernel<<<(NLAYERS * 4096 + 255) / 256, 256, 0, stream>>>(Wl, Wr, wpk);

    // ---- embed + LN ----
    embed_ln_kernel<<<(NNODES * 64 + 255) / 256, 256, 0, stream>>>(
        node_emb, pos, pos_tab, eg, eb, (u32*)xh);

    // ---- layers ----
    for (int l = 0; l < NLAYERS; ++l) {
        gather_kernel<<<(NNODES * 64 + 255) / 256, 256, 0, stream>>>(
            offsets, srcs, (const uint4*)xh, (uint4*)agg);

        sage_mfma_kernel<<<(NNODES + 63) / 64, 256, 0, stream>>>(
            agg, xh,
            wpk + (size_t)l * 4096 * 8,
            bl + (size_t)l * DDIM,
            hg + (size_t)l * DDIM,
            hb + (size_t)l * DDIM,
            (l == NLAYERS - 1) ? (float*)d_out : (float*)nullptr);
    }
}

// Round 7
// 335.405 us; speedup vs baseline: 7.9881x; 1.0427x over previous
//
#include <hip/hip_runtime.h>

#define DDIM    128
#define NNODES  50000
#define NEDGES  800000
#define NLAYERS 3
#define LN_EPS  1e-5f
#define NSCAN   ((NNODES + 255) / 256)
#define NSLICE  8
#define SLICESZ ((NNODES + NSLICE - 1) / NSLICE)              // 6250
#define FILL_EPT 8
#define FILL_CHUNK (256 * FILL_EPT)                           // 2048
#define FILL_NCHUNK ((NEDGES + FILL_CHUNK - 1) / FILL_CHUNK)  // 391

typedef short s16x8 __attribute__((ext_vector_type(8)));
typedef float f32x4 __attribute__((ext_vector_type(4)));
typedef unsigned int u32;

__device__ __forceinline__ unsigned short f2bf(float f) {
    union { float f; unsigned u; } c; c.f = f;
    unsigned r = c.u + 0x7fff + ((c.u >> 16) & 1);   // RNE
    return (unsigned short)(r >> 16);
}
__device__ __forceinline__ float bf2f_u(unsigned short h) {
    union { unsigned u; float f; } c; c.u = (unsigned)h << 16;
    return c.f;
}
__device__ __forceinline__ float bflo(u32 v) { return __uint_as_float(v << 16); }
__device__ __forceinline__ float bfhi(u32 v) { return __uint_as_float(v & 0xffff0000u); }

// ---------------------------------------------------------------------------
// CSR build
// ---------------------------------------------------------------------------
__global__ __launch_bounds__(256) void hist_kernel(
    const int* __restrict__ edge, int* __restrict__ deg)
{
    int e = blockIdx.x * 256 + threadIdx.x;
    if (e < NEDGES) atomicAdd(&deg[edge[NEDGES + e]], 1);
}

__global__ __launch_bounds__(256) void scan_part_kernel(
    const int* __restrict__ deg, int* __restrict__ offsets, int* __restrict__ partials)
{
    __shared__ int tmp[256];
    int t = threadIdx.x, i = blockIdx.x * 256 + t;
    int v = (i < NNODES) ? deg[i] : 0;
    tmp[t] = v; __syncthreads();
    for (int d = 1; d < 256; d <<= 1) {
        int add = (t >= d) ? tmp[t - d] : 0;
        __syncthreads();
        tmp[t] += add;
        __syncthreads();
    }
    if (i < NNODES) offsets[i + 1] = tmp[t];
    if (t == 255) partials[blockIdx.x] = tmp[255];
}

__global__ __launch_bounds__(256) void scan_tot_kernel(
    const int* __restrict__ partials, int* __restrict__ partoff)
{
    __shared__ int tmp[256];
    int t = threadIdx.x;
    int v = (t < NSCAN) ? partials[t] : 0;
    tmp[t] = v; __syncthreads();
    for (int d = 1; d < 256; d <<= 1) {
        int add = (t >= d) ? tmp[t - d] : 0;
        __syncthreads();
        tmp[t] += add;
        __syncthreads();
    }
    partoff[t] = tmp[t] - v;
}

__global__ __launch_bounds__(256) void scan_add_kernel(
    int* __restrict__ offsets, const int* __restrict__ partoff)
{
    int t = threadIdx.x, i = blockIdx.x * 256 + t;
    if (i < NNODES) offsets[i + 1] += partoff[blockIdx.x];
    if (i == 0) offsets[0] = 0;
}

// XCD-sliced fill: block b -> dst slice (b&7), edge chunk (b>>3).
__global__ __launch_bounds__(256) void fill_kernel(
    const int* __restrict__ edge, const int* __restrict__ offsets,
    int* __restrict__ cursor, int* __restrict__ srcs)
{
    int slice = blockIdx.x & (NSLICE - 1);
    int chunk = blockIdx.x >> 3;
    int lo = slice * SLICESZ;
    int hi = lo + SLICESZ;
    int base = chunk * FILL_CHUNK + threadIdx.x;
    #pragma unroll
    for (int i = 0; i < FILL_EPT; ++i) {
        int e = base + i * 256;
        if (e < NEDGES) {
            int d = edge[NEDGES + e];
            if (d >= lo && d < hi) {
                int s = edge[e];
                int slot = atomicAdd(&cursor[d], 1);
                srcs[offsets[d] + slot] = s;
            }
        }
    }
}

// ---------------------------------------------------------------------------
// Wcat prepack: [Wl;Wr] fp32 -> bf16 in MFMA B-fragment order, per layer.
// ---------------------------------------------------------------------------
__global__ __launch_bounds__(256) void wpack_kernel(
    const float* __restrict__ Wl,
    const float* __restrict__ Wr,
    unsigned short* __restrict__ wpk)
{
    int idx = blockIdx.x * 256 + threadIdx.x;
    if (idx >= NLAYERS * 4096) return;
    int l   = idx >> 12;
    int rem = idx & 4095;
    int kt = rem >> 9, ct = (rem >> 6) & 7, ln = rem & 63;
    int k0 = kt * 32 + ((ln >> 4) << 3);
    int c  = ct * 16 + (ln & 15);
    const float* src = (kt < 4)
        ? Wl + (size_t)l * DDIM * DDIM + (size_t)k0 * DDIM + c
        : Wr + (size_t)l * DDIM * DDIM + (size_t)(k0 - 128) * DDIM + c;
    s16x8 o;
    #pragma unroll
    for (int j = 0; j < 8; ++j) o[j] = (short)f2bf(src[j * DDIM]);
    *(s16x8*)(wpk + (size_t)idx * 8) = o;
}

// ---------------------------------------------------------------------------
// K0: embed + LN -> xh (bf16)
// ---------------------------------------------------------------------------
__global__ __launch_bounds__(256) void embed_ln_kernel(
    const float* __restrict__ node_emb,
    const int* __restrict__ pos,
    const float* __restrict__ pos_table,
    const float* __restrict__ g,
    const float* __restrict__ b,
    u32* __restrict__ xh32)
{
    int wid  = (blockIdx.x * blockDim.x + threadIdx.x) >> 6;
    int lane = threadIdx.x & 63;
    if (wid >= NNODES) return;

    const float scale = 11.313708498984761f;  // sqrt(128)
    int p = pos[wid];

    float2 ne = *(const float2*)(node_emb + (size_t)wid * DDIM + lane * 2);
    float2 pt = *(const float2*)(pos_table + (size_t)p * DDIM + lane * 2);
    float v0 = ne.x * scale + pt.x;
    float v1 = ne.y * scale + pt.y;

    float s  = v0 + v1;
    float s2 = v0 * v0 + v1 * v1;
    #pragma unroll
    for (int m = 32; m > 0; m >>= 1) {
        s  += __shfl_xor(s,  m, 64);
        s2 += __shfl_xor(s2, m, 64);
    }
    float mean = s * (1.0f / DDIM);
    float var  = s2 * (1.0f / DDIM) - mean * mean;
    float rstd = rsqrtf(var + LN_EPS);

    float2 gv = *(const float2*)(g + lane * 2);
    float2 bv = *(const float2*)(b + lane * 2);
    float y0 = (v0 - mean) * rstd * gv.x + bv.x;
    float y1 = (v1 - mean) * rstd * gv.y + bv.y;
    xh32[(size_t)wid * 64 + lane] = (u32)f2bf(y0) | ((u32)f2bf(y1) << 16);
}

// ---------------------------------------------------------------------------
// K1: gather, chunk-32 MLP: wave per node; lane (q,cl); chunk c handles
// neighbors j+c*4+q. Phase 1: burst-load 8 src indices. Phase 2: burst-issue
// 8 uint4 row-loads (exec-masked tail). Phase 3: accumulate. One batch covers
// deg<=32 (>99.9% of nodes): 8 row loads in flight per wave.
// ---------------------------------------------------------------------------
__global__ __launch_bounds__(256) void gather_kernel(
    const int* __restrict__ offsets,
    const int* __restrict__ srcs,
    const uint4* __restrict__ xh4,     // row = 16 uint4
    uint4* __restrict__ agg4)
{
    int wid  = (blockIdx.x * 256 + threadIdx.x) >> 6;
    int lane = threadIdx.x & 63;
    if (wid >= NNODES) return;
    int q = lane >> 4, cl = lane & 15;

    int beg = offsets[wid];
    int end = offsets[wid + 1];

    float acc[8];
    #pragma unroll
    for (int k = 0; k < 8; ++k) acc[k] = 0.0f;

    for (int j = beg; j < end; j += 32) {
        // phase 1: src indices, 8 independent 4B loads
        int sidx[8];
        #pragma unroll
        for (int c = 0; c < 8; ++c) {
            int jj = j + c * 4 + q;
            sidx[c] = (jj < end) ? srcs[jj] : -1;
        }
        // phase 2: 8 independent 16B row loads (exec-masked on tail)
        uint4 u[8];
        #pragma unroll
        for (int c = 0; c < 8; ++c) {
            u[c] = make_uint4(0u, 0u, 0u, 0u);
            if (sidx[c] >= 0)
                u[c] = xh4[(size_t)sidx[c] * 16 + cl];
        }
        // phase 3: accumulate
        #pragma unroll
        for (int c = 0; c < 8; ++c) {
            acc[0] += bflo(u[c].x); acc[1] += bfhi(u[c].x);
            acc[2] += bflo(u[c].y); acc[3] += bfhi(u[c].y);
            acc[4] += bflo(u[c].z); acc[5] += bfhi(u[c].z);
            acc[6] += bflo(u[c].w); acc[7] += bfhi(u[c].w);
        }
    }

    #pragma unroll
    for (int k = 0; k < 8; ++k) {
        acc[k] += __shfl_xor(acc[k], 16, 64);
        acc[k] += __shfl_xor(acc[k], 32, 64);
    }

    if (q == 0) {
        uint4 o;
        o.x = (u32)f2bf(acc[0]) | ((u32)f2bf(acc[1]) << 16);
        o.y = (u32)f2bf(acc[2]) | ((u32)f2bf(acc[3]) << 16);
        o.z = (u32)f2bf(acc[4]) | ((u32)f2bf(acc[5]) << 16);
        o.w = (u32)f2bf(acc[6]) | ((u32)f2bf(acc[7]) << 16);
        agg4[(size_t)wid * 16 + cl] = o;
    }
}

// ---------------------------------------------------------------------------
// K2: MFMA sage layer (unchanged from R6)
// ---------------------------------------------------------------------------
__global__ __launch_bounds__(256) void sage_mfma_kernel(
    const unsigned short* __restrict__ agg,   // bf16 [N][128]
    unsigned short* __restrict__ xh,          // bf16 [N][128], in/out
    const unsigned short* __restrict__ wpk,   // this layer, B-frag order
    const float* __restrict__ bl,
    const float* __restrict__ g,
    const float* __restrict__ b,
    float* __restrict__ xout)                 // d_out on last layer, else null
{
    __shared__ unsigned short wlds[4096 * 8];   // 64 KB

    int t    = threadIdx.x;
    int wave = t >> 6;
    int lane = t & 63;
    int cl   = lane & 15;
    int q    = lane >> 4;

    {
        const s16x8* srcv = (const s16x8*)wpk;
        s16x8* dstv = (s16x8*)wlds;
        for (int i = t; i < 4096; i += 256) dstv[i] = srcv[i];
    }
    __syncthreads();

    float bias[8], gg[8], bb[8];
    #pragma unroll
    for (int ct = 0; ct < 8; ++ct) {
        int c = ct * 16 + cl;
        bias[ct] = bl[c]; gg[ct] = g[c]; bb[ct] = b[c];
    }

    int m0 = blockIdx.x * 64 + wave * 16;
    int m  = m0 + cl;
    int mc = (m < NNODES) ? m : (NNODES - 1);

    s16x8 af[8];
    #pragma unroll
    for (int kt = 0; kt < 4; ++kt)
        af[kt] = *(const s16x8*)(agg + (size_t)mc * DDIM + kt * 32 + q * 8);
    #pragma unroll
    for (int kt = 4; kt < 8; ++kt)
        af[kt] = *(const s16x8*)(xh + (size_t)mc * DDIM + (kt - 4) * 32 + q * 8);

    f32x4 acc[8];
    #pragma unroll
    for (int ct = 0; ct < 8; ++ct) acc[ct] = (f32x4){0.f, 0.f, 0.f, 0.f};

    #pragma unroll
    for (int kt = 0; kt < 8; ++kt) {
        #pragma unroll
        for (int ct = 0; ct < 8; ++ct) {
            s16x8 bfr = *(const s16x8*)&wlds[((((kt << 3) + ct) << 6) + lane) * 8];
            acc[ct] = __builtin_amdgcn_mfma_f32_16x16x32_bf16(af[kt], bfr, acc[ct], 0, 0, 0);
        }
    }

    float hbuf[8][4];
    #pragma unroll
    for (int ct = 0; ct < 8; ++ct) {
        #pragma unroll
        for (int r = 0; r < 4; ++r) {
            int node = m0 + q * 4 + r;
            int nc   = (node < NNODES) ? node : (NNODES - 1);
            float hv = fmaxf(acc[ct][r] + bias[ct], 0.0f);
            hbuf[ct][r] = hv + bf2f_u(xh[(size_t)nc * DDIM + ct * 16 + cl]);
        }
    }

    float s[4], s2[4];
    #pragma unroll
    for (int r = 0; r < 4; ++r) {
        float a0 = 0.f, a1 = 0.f;
        #pragma unroll
        for (int ct = 0; ct < 8; ++ct) {
            a0 += hbuf[ct][r];
            a1 += hbuf[ct][r] * hbuf[ct][r];
        }
        #pragma unroll
        for (int msk = 1; msk < 16; msk <<= 1) {
            a0 += __shfl_xor(a0, msk, 64);
            a1 += __shfl_xor(a1, msk, 64);
        }
        s[r] = a0; s2[r] = a1;
    }

    #pragma unroll
    for (int r = 0; r < 4; ++r) {
        int node = m0 + q * 4 + r;
        if (node >= NNODES) continue;
        float mean = s[r] * (1.0f / DDIM);
        float var  = s2[r] * (1.0f / DDIM) - mean * mean;
        float rstd = rsqrtf(var + LN_EPS);
        #pragma unroll
        for (int ct = 0; ct < 8; ++ct) {
            float y = (hbuf[ct][r] - mean) * rstd * gg[ct] + bb[ct];
            size_t off = (size_t)node * DDIM + ct * 16 + cl;
            xh[off] = f2bf(y);
            if (xout) xout[off] = y;
        }
    }
}

// ---------------------------------------------------------------------------
extern "C" void kernel_launch(void* const* d_in, const int* in_sizes, int n_in,
                              void* d_out, int out_size, void* d_ws, size_t ws_size,
                              hipStream_t stream)
{
    const float* node_emb = (const float*)d_in[0];
    const int*   pos      = (const int*)d_in[1];
    const int*   edge     = (const int*)d_in[2];
    const float* pos_tab  = (const float*)d_in[3];
    const float* Wl       = (const float*)d_in[4];
    const float* bl       = (const float*)d_in[5];
    const float* Wr       = (const float*)d_in[6];
    const float* eg       = (const float*)d_in[7];
    const float* eb       = (const float*)d_in[8];
    const float* hg       = (const float*)d_in[9];
    const float* hb       = (const float*)d_in[10];

    // workspace: [xh bf16][agg bf16][wpk bf16][CSR ints]
    unsigned short* xh  = (unsigned short*)d_ws;
    unsigned short* agg = xh + (size_t)NNODES * DDIM;
    unsigned short* wpk = agg + (size_t)NNODES * DDIM;
    int* deg      = (int*)(wpk + (size_t)NLAYERS * 4096 * 8);
    int* cursor   = deg + NNODES;
    int* offsets  = cursor + NNODES;
    int* partials = offsets + NNODES + 2;
    int* partoff  = partials + 256;
    int* srcs     = partoff + 256;

    // ---- CSR build (edges constant across layers) ----
    hipMemsetAsync(deg, 0, 2 * NNODES * sizeof(int), stream);
    hist_kernel<<<(NEDGES + 255) / 256, 256, 0, stream>>>(edge, deg);
    scan_part_kernel<<<NSCAN, 256, 0, stream>>>(deg, offsets, partials);
    scan_tot_kernel<<<1, 256, 0, stream>>>(partials, partoff);
    scan_add_kernel<<<NSCAN, 256, 0, stream>>>(offsets, partoff);
    fill_kernel<<<FILL_NCHUNK * NSLICE, 256, 0, stream>>>(edge, offsets, cursor, srcs);

    // ---- W prepack (all layers) ----
    wpack_kernel<<<(NLAYERS * 4096 + 255) / 256, 256, 0, stream>>>(Wl, Wr, wpk);

    // ---- embed + LN ----
    embed_ln_kernel<<<(NNODES * 64 + 255) / 256, 256, 0, stream>>>(
        node_emb, pos, pos_tab, eg, eb, (u32*)xh);

    // ---- layers ----
    for (int l = 0; l < NLAYERS; ++l) {
        gather_kernel<<<(NNODES * 64 + 255) / 256, 256, 0, stream>>>(
            offsets, srcs, (const uint4*)xh, (uint4*)agg);

        sage_mfma_kernel<<<(NNODES + 63) / 64, 256, 0, stream>>>(
            agg, xh,
            wpk + (size_t)l * 4096 * 8,
            bl + (size_t)l * DDIM,
            hg + (size_t)l * DDIM,
            hb + (size_t)l * DDIM,
            (l == NLAYERS - 1) ? (float*)d_out : (float*)nullptr);
    }
}